// Round 2
// baseline (975.648 us; speedup 1.0000x reference)
//
#include <hip/hip_runtime.h>

#define NBATCH 8
#define NROWS 2048
#define MDIM 128
#define NITER 50
#define RT_STR 66   // f64 row stride for sRT ([j][r], 64 rows + pad)

// ---------------------------------------------------------------------------
// mk_m64: M = I + 2*Vs*Vs^T (f64), X0 = 2I - M.  grid 32 = 8b x 4 (64x64 tiles)
// ---------------------------------------------------------------------------
__global__ __launch_bounds__(256) void mk_m64(const float* __restrict__ V,
                                              double* __restrict__ M,
                                              double* __restrict__ X0) {
  __shared__ double sA[64][131];
  __shared__ double sB[64][131];
  const int b = blockIdx.x >> 2, t = blockIdx.x & 3;
  const int i0 = (t >> 1) << 6, j0 = (t & 1) << 6;
  const float* Vb = V + b * MDIM * MDIM;
  const int tid = threadIdx.x;
  const double S = 1.0 / 128.0;
  for (int idx = tid; idx < 2048; idx += 256) {
    const int r = idx >> 5, c4 = (idx & 31) << 2;
    float4 v = *(const float4*)(Vb + (i0 + r) * MDIM + c4);
    sA[r][c4 + 0] = v.x * S; sA[r][c4 + 1] = v.y * S;
    sA[r][c4 + 2] = v.z * S; sA[r][c4 + 3] = v.w * S;
    float4 w = *(const float4*)(Vb + (j0 + r) * MDIM + c4);
    sB[r][c4 + 0] = w.x * S; sB[r][c4 + 1] = w.y * S;
    sB[r][c4 + 2] = w.z * S; sB[r][c4 + 3] = w.w * S;
  }
  __syncthreads();
  const int tx = tid & 15, ty = tid >> 4;
  double acc[4][4] = {};
  for (int k = 0; k < 128; ++k) {
    double a0 = sA[ty * 4 + 0][k], a1 = sA[ty * 4 + 1][k];
    double a2 = sA[ty * 4 + 2][k], a3 = sA[ty * 4 + 3][k];
    double b0 = sB[tx * 4 + 0][k], b1 = sB[tx * 4 + 1][k];
    double b2 = sB[tx * 4 + 2][k], b3 = sB[tx * 4 + 3][k];
    acc[0][0] = fma(a0, b0, acc[0][0]); acc[0][1] = fma(a0, b1, acc[0][1]);
    acc[0][2] = fma(a0, b2, acc[0][2]); acc[0][3] = fma(a0, b3, acc[0][3]);
    acc[1][0] = fma(a1, b0, acc[1][0]); acc[1][1] = fma(a1, b1, acc[1][1]);
    acc[1][2] = fma(a1, b2, acc[1][2]); acc[1][3] = fma(a1, b3, acc[1][3]);
    acc[2][0] = fma(a2, b0, acc[2][0]); acc[2][1] = fma(a2, b1, acc[2][1]);
    acc[2][2] = fma(a2, b2, acc[2][2]); acc[2][3] = fma(a2, b3, acc[2][3]);
    acc[3][0] = fma(a3, b0, acc[3][0]); acc[3][1] = fma(a3, b1, acc[3][1]);
    acc[3][2] = fma(a3, b2, acc[3][2]); acc[3][3] = fma(a3, b3, acc[3][3]);
  }
  double* Mb = M + b * 16384;
  double* Xb = X0 + b * 16384;
#pragma unroll
  for (int i = 0; i < 4; ++i)
#pragma unroll
    for (int j = 0; j < 4; ++j) {
      const int gi = i0 + ty * 4 + i, gj = j0 + tx * 4 + j;
      const double diag = (gi == gj) ? 1.0 : 0.0;
      const double mv = 2.0 * acc[i][j] + diag;
      Mb[gi * 128 + gj] = mv;
      Xb[gi * 128 + gj] = 2.0 * diag - mv;
    }
}

// ---------------------------------------------------------------------------
// ns_gemm64: C = A * B^T-as-rows (B SYMMETRIC: reads B rows).  mode1: C = 2*Xc - A*B
// grid 32 = 8b x 4 (64x64 tiles)
// ---------------------------------------------------------------------------
__global__ __launch_bounds__(256) void ns_gemm64(const double* __restrict__ A,
                                                 const double* __restrict__ B,
                                                 double* __restrict__ C,
                                                 const double* __restrict__ Xc,
                                                 int mode) {
  __shared__ double sA[64][131];
  __shared__ double sB[64][131];
  const int b = blockIdx.x >> 2, t = blockIdx.x & 3;
  const int i0 = (t >> 1) << 6, j0 = (t & 1) << 6;
  const double* Ab = A + b * 16384;
  const double* Bb = B + b * 16384;
  const int tid = threadIdx.x;
  for (int idx = tid; idx < 4096; idx += 256) {
    const int r = idx >> 6, c2 = (idx & 63) << 1;
    *(double2*)&sA[r][c2] = *(const double2*)(Ab + (i0 + r) * 128 + c2);
    *(double2*)&sB[r][c2] = *(const double2*)(Bb + (j0 + r) * 128 + c2);
  }
  __syncthreads();
  const int tx = tid & 15, ty = tid >> 4;
  double acc[4][4] = {};
  for (int k = 0; k < 128; ++k) {
    double a0 = sA[ty * 4 + 0][k], a1 = sA[ty * 4 + 1][k];
    double a2 = sA[ty * 4 + 2][k], a3 = sA[ty * 4 + 3][k];
    double b0 = sB[tx * 4 + 0][k], b1 = sB[tx * 4 + 1][k];
    double b2 = sB[tx * 4 + 2][k], b3 = sB[tx * 4 + 3][k];
    acc[0][0] = fma(a0, b0, acc[0][0]); acc[0][1] = fma(a0, b1, acc[0][1]);
    acc[0][2] = fma(a0, b2, acc[0][2]); acc[0][3] = fma(a0, b3, acc[0][3]);
    acc[1][0] = fma(a1, b0, acc[1][0]); acc[1][1] = fma(a1, b1, acc[1][1]);
    acc[1][2] = fma(a1, b2, acc[1][2]); acc[1][3] = fma(a1, b3, acc[1][3]);
    acc[2][0] = fma(a2, b0, acc[2][0]); acc[2][1] = fma(a2, b1, acc[2][1]);
    acc[2][2] = fma(a2, b2, acc[2][2]); acc[2][3] = fma(a2, b3, acc[2][3]);
    acc[3][0] = fma(a3, b0, acc[3][0]); acc[3][1] = fma(a3, b1, acc[3][1]);
    acc[3][2] = fma(a3, b2, acc[3][2]); acc[3][3] = fma(a3, b3, acc[3][3]);
  }
  double* Cb = C + b * 16384;
  const double* Xcb = Xc + b * 16384;
#pragma unroll
  for (int i = 0; i < 4; ++i)
#pragma unroll
    for (int j = 0; j < 4; ++j) {
      const int gi = i0 + ty * 4 + i, gj = j0 + tx * 4 + j;
      double v = acc[i][j];
      if (mode != 0) v = 2.0 * Xcb[gi * 128 + gj] - v;
      Cb[gi * 128 + gj] = v;
    }
}

// ---------------------------------------------------------------------------
// admm64: persistent f64 ADMM. grid 256 = 8b x 32 tiles(64 rows). 512 threads.
// thread tile: 2 rows x 8 cols.  rg=tid&31 (rows r0=2*rg), cg=tid>>5 (cols c0=8*cg)
// LDS: sP 64K (2 x 32x128 f64 panels) + sRT 66K + sCnt 4K = 134 KiB
// ---------------------------------------------------------------------------
__device__ __forceinline__ void gemm32(const double* __restrict__ pan,
                                       const double* __restrict__ rt,
                                       int r0, int c0, double acc[2][8]) {
#pragma unroll 8
  for (int jj = 0; jj < 32; ++jj) {
    const double2 a  = *(const double2*)(rt + jj * RT_STR + r0);
    const double2 m0 = *(const double2*)(pan + jj * 128 + c0 + 0);
    const double2 m1 = *(const double2*)(pan + jj * 128 + c0 + 2);
    const double2 m2 = *(const double2*)(pan + jj * 128 + c0 + 4);
    const double2 m3 = *(const double2*)(pan + jj * 128 + c0 + 6);
    acc[0][0] = fma(a.x, m0.x, acc[0][0]); acc[0][1] = fma(a.x, m0.y, acc[0][1]);
    acc[0][2] = fma(a.x, m1.x, acc[0][2]); acc[0][3] = fma(a.x, m1.y, acc[0][3]);
    acc[0][4] = fma(a.x, m2.x, acc[0][4]); acc[0][5] = fma(a.x, m2.y, acc[0][5]);
    acc[0][6] = fma(a.x, m3.x, acc[0][6]); acc[0][7] = fma(a.x, m3.y, acc[0][7]);
    acc[1][0] = fma(a.y, m0.x, acc[1][0]); acc[1][1] = fma(a.y, m0.y, acc[1][1]);
    acc[1][2] = fma(a.y, m1.x, acc[1][2]); acc[1][3] = fma(a.y, m1.y, acc[1][3]);
    acc[1][4] = fma(a.y, m2.x, acc[1][4]); acc[1][5] = fma(a.y, m2.y, acc[1][5]);
    acc[1][6] = fma(a.y, m3.x, acc[1][6]); acc[1][7] = fma(a.y, m3.y, acc[1][7]);
  }
}

__global__ __launch_bounds__(512, 2) void admm64(const float* __restrict__ Q,
                                                 const float* __restrict__ V,
                                                 const double* __restrict__ Minv,
                                                 float* __restrict__ out) {
  __shared__ double sP[2][32 * 128];
  __shared__ double sRT[128 * RT_STR];
  __shared__ float sCnt[64 * 16];
  const int tid = threadIdx.x;
  const int b = blockIdx.x >> 5;
  const int n0 = (blockIdx.x & 31) << 6;
  const int rg = tid & 31, cg = tid >> 5;
  const int r0 = rg << 1, c0 = cg << 3;
  const float* Qb = Q + ((size_t)b * NROWS + n0) * MDIM;
  const float* Vb = V + b * MDIM * MDIM;
  const double* Mb = Minv + (size_t)b * MDIM * MDIM;
  float* outb = out + ((size_t)b * NROWS + n0) * MDIM;
  const double S = 1.0 / 128.0;

  // ---- stage Q^T (f64) into sRT[d][r]
  for (int idx = tid; idx < 2048; idx += 512) {
    const int r = idx >> 5, d4 = (idx & 31) << 2;
    float4 q = *(const float4*)(Qb + r * MDIM + d4);
    sRT[(d4 + 0) * RT_STR + r] = (double)q.x;
    sRT[(d4 + 1) * RT_STR + r] = (double)q.y;
    sRT[(d4 + 2) * RT_STR + r] = (double)q.z;
    sRT[(d4 + 3) * RT_STR + r] = (double)q.w;
  }
  // ---- stage VsT panel 0: buf[jj*128 + m] = Vs[m][d0+jj]
#define STAGE_VST(d0, buf)                                                \
  for (int idx = tid; idx < 1024; idx += 512) {                           \
    const int m_ = idx >> 3, j4 = (idx & 7) << 2;                         \
    float4 vv = *(const float4*)(Vb + m_ * 128 + (d0) + j4);              \
    (buf)[(j4 + 0) * 128 + m_] = vv.x * S;                                \
    (buf)[(j4 + 1) * 128 + m_] = vv.y * S;                                \
    (buf)[(j4 + 2) * 128 + m_] = vv.z * S;                                \
    (buf)[(j4 + 3) * 128 + m_] = vv.w * S;                                \
  }
#define STAGE_VS(m0, buf)                                                 \
  for (int idx = tid; idx < 1024; idx += 512) {                           \
    const int jj = idx >> 5, d4 = (idx & 31) << 2;                        \
    float4 vv = *(const float4*)(Vb + ((m0) + jj) * 128 + d4);            \
    (buf)[jj * 128 + d4 + 0] = vv.x * S;                                  \
    (buf)[jj * 128 + d4 + 1] = vv.y * S;                                  \
    (buf)[jj * 128 + d4 + 2] = vv.z * S;                                  \
    (buf)[jj * 128 + d4 + 3] = vv.w * S;                                  \
  }
#define STAGE_M(p, buf)                                                   \
  {                                                                       \
    const double2* src_ = (const double2*)(Mb + (p) * 4096);              \
    double2* dst_ = (double2*)(buf);                                      \
    for (int idx = tid; idx < 2048; idx += 512) dst_[idx] = src_[idx];    \
  }

  STAGE_VST(0, sP[0]);
  __syncthreads();

  // ---- P = -2 * Q . Vs^T + lambda/m   (f64)
  double acc[2][8];
#pragma unroll
  for (int i = 0; i < 2; ++i)
#pragma unroll
    for (int c = 0; c < 8; ++c) acc[i][c] = 0.0;
  for (int pp = 0; pp < 4; ++pp) {
    if (pp < 3) { STAGE_VST((pp + 1) * 32, sP[(pp + 1) & 1]); }
    gemm32(sP[pp & 1], sRT + (pp * 32) * RT_STR, r0, c0, acc);
    __syncthreads();
  }
  const double LAM = 0.1 / 128.0;
  double pcf[2][8];
#pragma unroll
  for (int i = 0; i < 2; ++i)
#pragma unroll
    for (int c = 0; c < 8; ++c) pcf[i][c] = fma(-2.0, acc[i][c], LAM);

  // ---- ADMM main loop (all f64)
  double z[2][8] = {}, u[2][8] = {};
  for (int it = 0; it < NITER; ++it) {
#pragma unroll
    for (int cc = 0; cc < 8; ++cc) {
      double2 w;
      w.x = (z[0][cc] - u[0][cc]) - pcf[0][cc];
      w.y = (z[1][cc] - u[1][cc]) - pcf[1][cc];
      *(double2*)&sRT[(c0 + cc) * RT_STR + r0] = w;
    }
    STAGE_M(0, sP[0]);
    __syncthreads();
#pragma unroll
    for (int i = 0; i < 2; ++i)
#pragma unroll
      for (int c = 0; c < 8; ++c) acc[i][c] = 0.0;
    for (int pp = 0; pp < 4; ++pp) {
      if (pp < 3) { STAGE_M(pp + 1, sP[(pp + 1) & 1]); }
      gemm32(sP[pp & 1], sRT + (pp * 32) * RT_STR, r0, c0, acc);
      __syncthreads();
    }
#pragma unroll
    for (int i = 0; i < 2; ++i)
#pragma unroll
      for (int cc = 0; cc < 8; ++cc) {
        const double y = acc[i][cc] + u[i][cc];
        const double zn = fmin(fmax(y, 0.0), 1.0);
        u[i][cc] = y - zn;
        z[i][cc] = zn;
      }
  }

  // ---- epilogue: threshold, counts, coeffs, out = coeffs . Vs
  double xb[2][8];
  float cnt0 = 0.f, cnt1 = 0.f;
#pragma unroll
  for (int cc = 0; cc < 8; ++cc) {
    xb[0][cc] = (z[0][cc] > 0.5) ? 1.0 : 0.0;
    xb[1][cc] = (z[1][cc] > 0.5) ? 1.0 : 0.0;
    cnt0 += (float)xb[0][cc];
    cnt1 += (float)xb[1][cc];
  }
  sCnt[(r0 + 0) * 16 + cg] = cnt0;
  sCnt[(r0 + 1) * 16 + cg] = cnt1;
  STAGE_VS(0, sP[0]);
  __syncthreads();
  float k0 = 0.f, k1 = 0.f;
#pragma unroll
  for (int g = 0; g < 16; ++g) {
    k0 += sCnt[(r0 + 0) * 16 + g];
    k1 += sCnt[(r0 + 1) * 16 + g];
  }
  const double rk0 = 1.0 / ((double)k0 + 1e-10);
  const double rk1 = 1.0 / ((double)k1 + 1e-10);
#pragma unroll
  for (int cc = 0; cc < 8; ++cc) {
    double2 w;
    w.x = xb[0][cc] * rk0;
    w.y = xb[1][cc] * rk1;
    *(double2*)&sRT[(c0 + cc) * RT_STR + r0] = w;
  }
  __syncthreads();
#pragma unroll
  for (int i = 0; i < 2; ++i)
#pragma unroll
    for (int c = 0; c < 8; ++c) acc[i][c] = 0.0;
  for (int pp = 0; pp < 4; ++pp) {
    if (pp < 3) { STAGE_VS((pp + 1) * 32, sP[(pp + 1) & 1]); }
    gemm32(sP[pp & 1], sRT + (pp * 32) * RT_STR, r0, c0, acc);
    __syncthreads();
  }
#pragma unroll
  for (int i = 0; i < 2; ++i) {
    float4 o0, o1;
    o0.x = (float)acc[i][0]; o0.y = (float)acc[i][1];
    o0.z = (float)acc[i][2]; o0.w = (float)acc[i][3];
    o1.x = (float)acc[i][4]; o1.y = (float)acc[i][5];
    o1.z = (float)acc[i][6]; o1.w = (float)acc[i][7];
    *(float4*)(outb + (r0 + i) * 128 + c0 + 0) = o0;
    *(float4*)(outb + (r0 + i) * 128 + c0 + 4) = o1;
  }
}

// ---------------------------------------------------------------------------
extern "C" void kernel_launch(void* const* d_in, const int* in_sizes, int n_in,
                              void* d_out, int out_size, void* d_ws, size_t ws_size,
                              hipStream_t stream) {
  const float* Q = (const float*)d_in[0];
  const float* V = (const float*)d_in[1];
  float* out = (float*)d_out;
  double* ws = (double*)d_ws;
  double* Mw = ws;                // 8*16384 f64 = 1 MiB
  double* Xa = ws + 131072;
  double* Xb = ws + 262144;
  double* Tw = ws + 393216;       // total 4 MiB

  mk_m64<<<32, 256, 0, stream>>>(V, Mw, Xa);
  double* pa = Xa;
  double* pb = Xb;
  for (int i = 0; i < 3; ++i) {  // Newton-Schulz in f64: residual ||E||^(2^(k+1)) -> ~6e-20
    ns_gemm64<<<32, 256, 0, stream>>>(pa, Mw, Tw, pa, 0);  // T = X*M   (B=M symmetric)
    ns_gemm64<<<32, 256, 0, stream>>>(Tw, pa, pb, pa, 1);  // X' = 2X - T*X  (B=X symmetric)
    double* tmp = pa; pa = pb; pb = tmp;
  }
  admm64<<<256, 512, 0, stream>>>(Q, V, pa, out);
}

// Round 3
// 643.459 us; speedup vs baseline: 1.5163x; 1.5163x over previous
//
#include <hip/hip_runtime.h>

#define NBATCH 8
#define NROWS 2048
#define MDIM 128
#define NITER 50

// ---------------------------------------------------------------------------
// mk_m64: M = I + 2*Vs*Vs^T (f64), X0 = 2I - M.  grid 32 = 8b x 4 (64x64 tiles)
// (unchanged from R2 — correctness anchor)
// ---------------------------------------------------------------------------
__global__ __launch_bounds__(256) void mk_m64(const float* __restrict__ V,
                                              double* __restrict__ M,
                                              double* __restrict__ X0) {
  __shared__ double sA[64][131];
  __shared__ double sB[64][131];
  const int b = blockIdx.x >> 2, t = blockIdx.x & 3;
  const int i0 = (t >> 1) << 6, j0 = (t & 1) << 6;
  const float* Vb = V + b * MDIM * MDIM;
  const int tid = threadIdx.x;
  const double S = 1.0 / 128.0;
  for (int idx = tid; idx < 2048; idx += 256) {
    const int r = idx >> 5, c4 = (idx & 31) << 2;
    float4 v = *(const float4*)(Vb + (i0 + r) * MDIM + c4);
    sA[r][c4 + 0] = v.x * S; sA[r][c4 + 1] = v.y * S;
    sA[r][c4 + 2] = v.z * S; sA[r][c4 + 3] = v.w * S;
    float4 w = *(const float4*)(Vb + (j0 + r) * MDIM + c4);
    sB[r][c4 + 0] = w.x * S; sB[r][c4 + 1] = w.y * S;
    sB[r][c4 + 2] = w.z * S; sB[r][c4 + 3] = w.w * S;
  }
  __syncthreads();
  const int tx = tid & 15, ty = tid >> 4;
  double acc[4][4] = {};
  for (int k = 0; k < 128; ++k) {
    double a0 = sA[ty * 4 + 0][k], a1 = sA[ty * 4 + 1][k];
    double a2 = sA[ty * 4 + 2][k], a3 = sA[ty * 4 + 3][k];
    double b0 = sB[tx * 4 + 0][k], b1 = sB[tx * 4 + 1][k];
    double b2 = sB[tx * 4 + 2][k], b3 = sB[tx * 4 + 3][k];
    acc[0][0] = fma(a0, b0, acc[0][0]); acc[0][1] = fma(a0, b1, acc[0][1]);
    acc[0][2] = fma(a0, b2, acc[0][2]); acc[0][3] = fma(a0, b3, acc[0][3]);
    acc[1][0] = fma(a1, b0, acc[1][0]); acc[1][1] = fma(a1, b1, acc[1][1]);
    acc[1][2] = fma(a1, b2, acc[1][2]); acc[1][3] = fma(a1, b3, acc[1][3]);
    acc[2][0] = fma(a2, b0, acc[2][0]); acc[2][1] = fma(a2, b1, acc[2][1]);
    acc[2][2] = fma(a2, b2, acc[2][2]); acc[2][3] = fma(a2, b3, acc[2][3]);
    acc[3][0] = fma(a3, b0, acc[3][0]); acc[3][1] = fma(a3, b1, acc[3][1]);
    acc[3][2] = fma(a3, b2, acc[3][2]); acc[3][3] = fma(a3, b3, acc[3][3]);
  }
  double* Mb = M + b * 16384;
  double* Xb = X0 + b * 16384;
#pragma unroll
  for (int i = 0; i < 4; ++i)
#pragma unroll
    for (int j = 0; j < 4; ++j) {
      const int gi = i0 + ty * 4 + i, gj = j0 + tx * 4 + j;
      const double diag = (gi == gj) ? 1.0 : 0.0;
      const double mv = 2.0 * acc[i][j] + diag;
      Mb[gi * 128 + gj] = mv;
      Xb[gi * 128 + gj] = 2.0 * diag - mv;
    }
}

// ---------------------------------------------------------------------------
// ns_gemm64: C = A*B (B symmetric, read rows). mode1: C = 2*Xc - A*B (unchanged)
// ---------------------------------------------------------------------------
__global__ __launch_bounds__(256) void ns_gemm64(const double* __restrict__ A,
                                                 const double* __restrict__ B,
                                                 double* __restrict__ C,
                                                 const double* __restrict__ Xc,
                                                 int mode) {
  __shared__ double sA[64][131];
  __shared__ double sB[64][131];
  const int b = blockIdx.x >> 2, t = blockIdx.x & 3;
  const int i0 = (t >> 1) << 6, j0 = (t & 1) << 6;
  const double* Ab = A + b * 16384;
  const double* Bb = B + b * 16384;
  const int tid = threadIdx.x;
  for (int idx = tid; idx < 4096; idx += 256) {
    const int r = idx >> 6, c2 = (idx & 63) << 1;
    *(double2*)&sA[r][c2] = *(const double2*)(Ab + (i0 + r) * 128 + c2);
    *(double2*)&sB[r][c2] = *(const double2*)(Bb + (j0 + r) * 128 + c2);
  }
  __syncthreads();
  const int tx = tid & 15, ty = tid >> 4;
  double acc[4][4] = {};
  for (int k = 0; k < 128; ++k) {
    double a0 = sA[ty * 4 + 0][k], a1 = sA[ty * 4 + 1][k];
    double a2 = sA[ty * 4 + 2][k], a3 = sA[ty * 4 + 3][k];
    double b0 = sB[tx * 4 + 0][k], b1 = sB[tx * 4 + 1][k];
    double b2 = sB[tx * 4 + 2][k], b3 = sB[tx * 4 + 3][k];
    acc[0][0] = fma(a0, b0, acc[0][0]); acc[0][1] = fma(a0, b1, acc[0][1]);
    acc[0][2] = fma(a0, b2, acc[0][2]); acc[0][3] = fma(a0, b3, acc[0][3]);
    acc[1][0] = fma(a1, b0, acc[1][0]); acc[1][1] = fma(a1, b1, acc[1][1]);
    acc[1][2] = fma(a1, b2, acc[1][2]); acc[1][3] = fma(a1, b3, acc[1][3]);
    acc[2][0] = fma(a2, b0, acc[2][0]); acc[2][1] = fma(a2, b1, acc[2][1]);
    acc[2][2] = fma(a2, b2, acc[2][2]); acc[2][3] = fma(a2, b3, acc[2][3]);
    acc[3][0] = fma(a3, b0, acc[3][0]); acc[3][1] = fma(a3, b1, acc[3][1]);
    acc[3][2] = fma(a3, b2, acc[3][2]); acc[3][3] = fma(a3, b3, acc[3][3]);
  }
  double* Cb = C + b * 16384;
  const double* Xcb = Xc + b * 16384;
#pragma unroll
  for (int i = 0; i < 4; ++i)
#pragma unroll
    for (int j = 0; j < 4; ++j) {
      const int gi = i0 + ty * 4 + i, gj = j0 + tx * 4 + j;
      double v = acc[i][j];
      if (mode != 0) v = 2.0 * Xcb[gi * 128 + gj] - v;
      Cb[gi * 128 + gj] = v;
    }
}

// ---------------------------------------------------------------------------
// prep_aux: W32 = fp32(I - Minv)  [j][c] row-major ;  VsT64[d][m] = f64 V[m][d]/128
// grid 8 (one per b), 256 threads
// ---------------------------------------------------------------------------
__global__ __launch_bounds__(256) void prep_aux(const double* __restrict__ Minv,
                                                const float* __restrict__ V,
                                                float* __restrict__ W32,
                                                double* __restrict__ VsT64) {
  const int b = blockIdx.x;
  const double* Mb = Minv + b * 16384;
  const float* Vb = V + b * 16384;
  float* Wb = W32 + b * 16384;
  double* Tb = VsT64 + b * 16384;
  for (int idx = threadIdx.x; idx < 16384; idx += 256) {
    const int j = idx >> 7, c = idx & 127;
    const double diag = (j == c) ? 1.0 : 0.0;
    Wb[idx] = (float)(diag - Mb[idx]);
    // VsT64[d][m] = V[m][d] / 128  (d=j, m=c)
    Tb[idx] = (double)Vb[c * 128 + j] * (1.0 / 128.0);
  }
}

// ---------------------------------------------------------------------------
// admm_corr: persistent ADMM, f64 state + fp32 correction GEMM.
// grid 256 = 8b x 32 tiles(64 rows). 512 threads = 8 waves.
// lane = row (0..63); wave w owns cols c0 = w*16 .. +15.
// x = Minv r = r - W r ;  W r computed fp32 with wave-uniform scalar W loads.
// LDS: sRT 32 KB ([j][n] f32) + sCnt 2 KB.
// ---------------------------------------------------------------------------
__global__ __launch_bounds__(512, 2) void admm_corr(const float* __restrict__ Q,
                                                    const float* __restrict__ V,
                                                    const float* __restrict__ W32,
                                                    const double* __restrict__ VsT64,
                                                    float* __restrict__ out) {
  __shared__ float sRT[128 * 64];
  __shared__ float sCnt[8 * 64];
  const int tid = threadIdx.x;
  const int b = blockIdx.x >> 5;
  const int n0 = (blockIdx.x & 31) << 6;
  const int lane = tid & 63;
  const int w = tid >> 6;
  const int c0 = w << 4;
  const int c0u = __builtin_amdgcn_readfirstlane(c0);  // wave-uniform col base -> SGPR
  const float* Qb = Q + ((size_t)(b * NROWS + n0)) * MDIM;
  const float* Wc = W32 + b * 16384 + c0u;
  const double* Vtc = VsT64 + b * 16384 + c0u;
  const float* Vc = V + b * 16384 + c0u;
  float* outb = out + ((size_t)(b * NROWS + n0)) * MDIM;

  // ---- stage Q^T (f32): sRT[d*64 + r] = Q[n0+r][d]
  for (int idx = tid; idx < 2048; idx += 512) {
    const int r = idx >> 5, d4 = (idx & 31) << 2;
    const float4 q = *(const float4*)(Qb + r * 128 + d4);
    sRT[(d4 + 0) * 64 + r] = q.x;
    sRT[(d4 + 1) * 64 + r] = q.y;
    sRT[(d4 + 2) * 64 + r] = q.z;
    sRT[(d4 + 3) * 64 + r] = q.w;
  }
  __syncthreads();

  // ---- P = -2 Q Vs^T + lam/m   (f64, same values & fma order as R2 -> bit-identical)
  double p[16];
#pragma unroll
  for (int c = 0; c < 16; ++c) p[c] = 0.0;
  for (int d = 0; d < 128; ++d) {
    const double a = (double)sRT[d * 64 + lane];
    const double* vt = Vtc + d * 128;
#pragma unroll
    for (int c = 0; c < 16; ++c) p[c] = fma(a, vt[c], p[c]);
  }
  const double LAM = 0.1 / 128.0;
#pragma unroll
  for (int c = 0; c < 16; ++c) p[c] = fma(-2.0, p[c], LAM);
  __syncthreads();

  // ---- ADMM loop: r f64 -> fp32 -> LDS ; corr = W r (fp32, scalar W) ; state f64
  double z[16], u[16], r64[16];
#pragma unroll
  for (int c = 0; c < 16; ++c) { z[c] = 0.0; u[c] = 0.0; }

  for (int it = 0; it < NITER; ++it) {
#pragma unroll
    for (int c = 0; c < 16; ++c) {
      const double rv = (z[c] - u[c]) - p[c];
      r64[c] = rv;
      sRT[(c0 + c) * 64 + lane] = (float)rv;   // conflict-free (64 consecutive)
    }
    __syncthreads();
    float acc[16];
#pragma unroll
    for (int c = 0; c < 16; ++c) acc[c] = 0.f;
    for (int jj = 0; jj < 128; jj += 4) {
      const float a0 = sRT[(jj + 0) * 64 + lane];
      const float a1 = sRT[(jj + 1) * 64 + lane];
      const float a2 = sRT[(jj + 2) * 64 + lane];
      const float a3 = sRT[(jj + 3) * 64 + lane];
      const float* w0 = Wc + (jj + 0) * 128;
      const float* w1 = Wc + (jj + 1) * 128;
      const float* w2 = Wc + (jj + 2) * 128;
      const float* w3 = Wc + (jj + 3) * 128;
#pragma unroll
      for (int c = 0; c < 16; ++c) acc[c] = fmaf(a0, w0[c], acc[c]);
#pragma unroll
      for (int c = 0; c < 16; ++c) acc[c] = fmaf(a1, w1[c], acc[c]);
#pragma unroll
      for (int c = 0; c < 16; ++c) acc[c] = fmaf(a2, w2[c], acc[c]);
#pragma unroll
      for (int c = 0; c < 16; ++c) acc[c] = fmaf(a3, w3[c], acc[c]);
    }
    __syncthreads();  // all reads done before next iteration's writes
#pragma unroll
    for (int c = 0; c < 16; ++c) {
      const double x = r64[c] - (double)acc[c];
      const double y = x + u[c];
      const double zn = fmin(fmax(y, 0.0), 1.0);
      u[c] = y - zn;
      z[c] = zn;
    }
  }

  // ---- epilogue: threshold, row count k, coeffs (x 1/128 folded), out = coeffs . V
  double xb[16];
  double cnt = 0.0;
#pragma unroll
  for (int c = 0; c < 16; ++c) {
    xb[c] = (z[c] > 0.5) ? 1.0 : 0.0;
    cnt += xb[c];
  }
  sCnt[w * 64 + lane] = (float)cnt;
  __syncthreads();
  double k = 0.0;
#pragma unroll
  for (int g = 0; g < 8; ++g) k += (double)sCnt[g * 64 + lane];
  const double rkS = (1.0 / 128.0) / (k + 1e-10);
#pragma unroll
  for (int c = 0; c < 16; ++c)
    sRT[(c0 + c) * 64 + lane] = (float)(xb[c] * rkS);
  __syncthreads();

  float oa[16];
#pragma unroll
  for (int c = 0; c < 16; ++c) oa[c] = 0.f;
  for (int m = 0; m < 128; m += 2) {
    const float a0 = sRT[(m + 0) * 64 + lane];
    const float a1 = sRT[(m + 1) * 64 + lane];
    const float* v0 = Vc + (m + 0) * 128;
    const float* v1 = Vc + (m + 1) * 128;
#pragma unroll
    for (int c = 0; c < 16; ++c) oa[c] = fmaf(a0, v0[c], oa[c]);
#pragma unroll
    for (int c = 0; c < 16; ++c) oa[c] = fmaf(a1, v1[c], oa[c]);
  }
#pragma unroll
  for (int q = 0; q < 4; ++q) {
    float4 o;
    o.x = oa[q * 4 + 0]; o.y = oa[q * 4 + 1];
    o.z = oa[q * 4 + 2]; o.w = oa[q * 4 + 3];
    *(float4*)(outb + lane * 128 + c0 + q * 4) = o;
  }
}

// ---------------------------------------------------------------------------
extern "C" void kernel_launch(void* const* d_in, const int* in_sizes, int n_in,
                              void* d_out, int out_size, void* d_ws, size_t ws_size,
                              hipStream_t stream) {
  const float* Q = (const float*)d_in[0];
  const float* V = (const float*)d_in[1];
  float* out = (float*)d_out;
  double* ws = (double*)d_ws;
  double* Mw = ws;                // 1 MiB (M; recycled as W32 after NS)
  double* Xa = ws + 131072;
  double* Xb = ws + 262144;
  double* Tw = ws + 393216;       // NS temp; recycled as VsT64. total 4 MiB

  mk_m64<<<32, 256, 0, stream>>>(V, Mw, Xa);
  double* pa = Xa;
  double* pb = Xb;
  for (int i = 0; i < 3; ++i) {  // Newton-Schulz f64: residual ||E||^(2^(k+1)) ~ 6e-20
    ns_gemm64<<<32, 256, 0, stream>>>(pa, Mw, Tw, pa, 0);  // T = X*M
    ns_gemm64<<<32, 256, 0, stream>>>(Tw, pa, pb, pa, 1);  // X' = 2X - T*X
    double* tmp = pa; pa = pb; pb = tmp;
  }
  // recycle: W32 -> Mw region (float), VsT64 -> Tw region (double)
  float* W32 = (float*)Mw;
  double* VsT64 = Tw;
  prep_aux<<<8, 256, 0, stream>>>(pa, V, W32, VsT64);
  admm_corr<<<256, 512, 0, stream>>>(Q, V, W32, VsT64, out);
}

// Round 4
// 499.636 us; speedup vs baseline: 1.9527x; 1.2879x over previous
//
#include <hip/hip_runtime.h>

#define NBATCH 8
#define NROWS 2048
#define MDIM 128
#define NITER 50

// ---------------------------------------------------------------------------
// mk_m64: M = I + 2*Vs*Vs^T (f64), X0 = 2I - M.
// grid 128 = 8b x 16 (32x32 tiles). Per-element fma chain identical to R2/R3.
// ---------------------------------------------------------------------------
__global__ __launch_bounds__(256) void mk_m64(const float* __restrict__ V,
                                              double* __restrict__ M,
                                              double* __restrict__ X0) {
  __shared__ double sA[32][130];
  __shared__ double sB[32][130];
  const int b = blockIdx.x >> 4, t = blockIdx.x & 15;
  const int i0 = (t >> 2) << 5, j0 = (t & 3) << 5;
  const float* Vb = V + b * MDIM * MDIM;
  const int tid = threadIdx.x;
  const double S = 1.0 / 128.0;
  for (int idx = tid; idx < 1024; idx += 256) {
    const int r = idx >> 5, c4 = (idx & 31) << 2;
    float4 v = *(const float4*)(Vb + (i0 + r) * MDIM + c4);
    sA[r][c4 + 0] = v.x * S; sA[r][c4 + 1] = v.y * S;
    sA[r][c4 + 2] = v.z * S; sA[r][c4 + 3] = v.w * S;
    float4 w = *(const float4*)(Vb + (j0 + r) * MDIM + c4);
    sB[r][c4 + 0] = w.x * S; sB[r][c4 + 1] = w.y * S;
    sB[r][c4 + 2] = w.z * S; sB[r][c4 + 3] = w.w * S;
  }
  __syncthreads();
  const int tx = tid & 15, ty = tid >> 4;
  double acc[2][2] = {};
  for (int k = 0; k < 128; ++k) {
    double a0 = sA[ty * 2 + 0][k], a1 = sA[ty * 2 + 1][k];
    double b0 = sB[tx * 2 + 0][k], b1 = sB[tx * 2 + 1][k];
    acc[0][0] = fma(a0, b0, acc[0][0]); acc[0][1] = fma(a0, b1, acc[0][1]);
    acc[1][0] = fma(a1, b0, acc[1][0]); acc[1][1] = fma(a1, b1, acc[1][1]);
  }
  double* Mb = M + b * 16384;
  double* Xb = X0 + b * 16384;
#pragma unroll
  for (int i = 0; i < 2; ++i)
#pragma unroll
    for (int j = 0; j < 2; ++j) {
      const int gi = i0 + ty * 2 + i, gj = j0 + tx * 2 + j;
      const double diag = (gi == gj) ? 1.0 : 0.0;
      const double mv = 2.0 * acc[i][j] + diag;
      Mb[gi * 128 + gj] = mv;
      Xb[gi * 128 + gj] = 2.0 * diag - mv;
    }
}

// ---------------------------------------------------------------------------
// ns_gemm64: C = A*B (B symmetric, read rows). mode1: C = 2*Xc - A*B.
// grid 128 = 8b x 16 (32x32 tiles). Per-element fma chain identical to R2/R3.
// ---------------------------------------------------------------------------
__global__ __launch_bounds__(256) void ns_gemm64(const double* __restrict__ A,
                                                 const double* __restrict__ B,
                                                 double* __restrict__ C,
                                                 const double* __restrict__ Xc,
                                                 int mode) {
  __shared__ double sA[32][130];
  __shared__ double sB[32][130];
  const int b = blockIdx.x >> 4, t = blockIdx.x & 15;
  const int i0 = (t >> 2) << 5, j0 = (t & 3) << 5;
  const double* Ab = A + b * 16384;
  const double* Bb = B + b * 16384;
  const int tid = threadIdx.x;
  for (int idx = tid; idx < 2048; idx += 256) {
    const int r = idx >> 6, c2 = (idx & 63) << 1;
    *(double2*)&sA[r][c2] = *(const double2*)(Ab + (i0 + r) * 128 + c2);
    *(double2*)&sB[r][c2] = *(const double2*)(Bb + (j0 + r) * 128 + c2);
  }
  __syncthreads();
  const int tx = tid & 15, ty = tid >> 4;
  double acc[2][2] = {};
  for (int k = 0; k < 128; ++k) {
    double a0 = sA[ty * 2 + 0][k], a1 = sA[ty * 2 + 1][k];
    double b0 = sB[tx * 2 + 0][k], b1 = sB[tx * 2 + 1][k];
    acc[0][0] = fma(a0, b0, acc[0][0]); acc[0][1] = fma(a0, b1, acc[0][1]);
    acc[1][0] = fma(a1, b0, acc[1][0]); acc[1][1] = fma(a1, b1, acc[1][1]);
  }
  double* Cb = C + b * 16384;
  const double* Xcb = Xc + b * 16384;
#pragma unroll
  for (int i = 0; i < 2; ++i)
#pragma unroll
    for (int j = 0; j < 2; ++j) {
      const int gi = i0 + ty * 2 + i, gj = j0 + tx * 2 + j;
      double v = acc[i][j];
      if (mode != 0) v = 2.0 * Xcb[gi * 128 + gj] - v;
      Cb[gi * 128 + gj] = v;
    }
}

// ---------------------------------------------------------------------------
// prep_aux: W32 = fp32(I - Minv) ;  VsT64[d][m] = f64 V[m][d]/128
// grid 64 = 8b x 8 chunks, 256 threads
// ---------------------------------------------------------------------------
__global__ __launch_bounds__(256) void prep_aux(const double* __restrict__ Minv,
                                                const float* __restrict__ V,
                                                float* __restrict__ W32,
                                                double* __restrict__ VsT64) {
  const int b = blockIdx.x >> 3, ch = blockIdx.x & 7;
  const double* Mb = Minv + b * 16384;
  const float* Vb = V + b * 16384;
  float* Wb = W32 + b * 16384;
  double* Tb = VsT64 + b * 16384;
  const int base = ch * 2048;
  for (int k = threadIdx.x; k < 2048; k += 256) {
    const int idx = base + k;
    const int j = idx >> 7, c = idx & 127;
    const double diag = (j == c) ? 1.0 : 0.0;
    Wb[idx] = (float)(diag - Mb[idx]);
    Tb[idx] = (double)Vb[c * 128 + j] * (1.0 / 128.0);
  }
}

// ---------------------------------------------------------------------------
// admm_corr: persistent ADMM, f64 state + fp32 correction GEMM.
// grid 256; b = blockIdx&7 (XCD-aligned: each XCD caches one batch's W in L2).
// 1024 threads = 16 waves (4 waves/SIMD). lane = row; wave w -> cols c0 = 8w.
// x = Minv r = r - W r ; W r in fp32 with wave-uniform scalar W loads.
// All per-element fma chains identical to R3 -> bit-identical trajectory.
// LDS: sRT 32 KB ([j][n] f32) + sCnt 4 KB.
// ---------------------------------------------------------------------------
__global__ __launch_bounds__(1024, 4) void admm_corr(const float* __restrict__ Q,
                                                     const float* __restrict__ V,
                                                     const float* __restrict__ W32,
                                                     const double* __restrict__ VsT64,
                                                     float* __restrict__ out) {
  __shared__ float sRT[128 * 64];
  __shared__ float sCnt[16 * 64];
  const int tid = threadIdx.x;
  const int b = blockIdx.x & 7;          // XCD id on 8-XCD MI355X
  const int n0 = (blockIdx.x >> 3) << 6; // 64-row tile
  const int lane = tid & 63;
  const int w = tid >> 6;                // 0..15
  const int c0 = w << 3;
  const int c0u = __builtin_amdgcn_readfirstlane(c0);  // wave-uniform -> SGPR
  const float* Qb = Q + ((size_t)(b * NROWS + n0)) * MDIM;
  const float* Wc = W32 + b * 16384 + c0u;
  const double* Vtc = VsT64 + b * 16384 + c0u;
  const float* Vc = V + b * 16384 + c0u;
  float* outb = out + ((size_t)(b * NROWS + n0)) * MDIM;

  // ---- stage Q^T (f32): sRT[d*64 + r] = Q[n0+r][d]
  for (int idx = tid; idx < 2048; idx += 1024) {
    const int r = idx >> 5, d4 = (idx & 31) << 2;
    const float4 q = *(const float4*)(Qb + r * 128 + d4);
    sRT[(d4 + 0) * 64 + r] = q.x;
    sRT[(d4 + 1) * 64 + r] = q.y;
    sRT[(d4 + 2) * 64 + r] = q.z;
    sRT[(d4 + 3) * 64 + r] = q.w;
  }
  __syncthreads();

  // ---- P = -2 Q Vs^T + lam/m   (f64, same fma chain as R3 -> bit-identical)
  double p[8];
#pragma unroll
  for (int c = 0; c < 8; ++c) p[c] = 0.0;
  for (int d = 0; d < 128; ++d) {
    const double a = (double)sRT[d * 64 + lane];
    const double* vt = Vtc + d * 128;
#pragma unroll
    for (int c = 0; c < 8; ++c) p[c] = fma(a, vt[c], p[c]);
  }
  const double LAM = 0.1 / 128.0;
#pragma unroll
  for (int c = 0; c < 8; ++c) p[c] = fma(-2.0, p[c], LAM);
  __syncthreads();

  // ---- ADMM loop: r f64 -> fp32 -> LDS ; corr = W r (fp32, scalar W) ; f64 state
  double z[8], u[8], r64[8];
#pragma unroll
  for (int c = 0; c < 8; ++c) { z[c] = 0.0; u[c] = 0.0; }

  for (int it = 0; it < NITER; ++it) {
#pragma unroll
    for (int c = 0; c < 8; ++c) {
      const double rv = (z[c] - u[c]) - p[c];
      r64[c] = rv;
      sRT[(c0 + c) * 64 + lane] = (float)rv;   // conflict-free b32 writes
    }
    __syncthreads();
    float acc[8];
#pragma unroll
    for (int c = 0; c < 8; ++c) acc[c] = 0.f;
    for (int jj = 0; jj < 128; jj += 4) {
      const float a0 = sRT[(jj + 0) * 64 + lane];
      const float a1 = sRT[(jj + 1) * 64 + lane];
      const float a2 = sRT[(jj + 2) * 64 + lane];
      const float a3 = sRT[(jj + 3) * 64 + lane];
      const float* w0 = Wc + (jj + 0) * 128;
      const float* w1 = Wc + (jj + 1) * 128;
      const float* w2 = Wc + (jj + 2) * 128;
      const float* w3 = Wc + (jj + 3) * 128;
#pragma unroll
      for (int c = 0; c < 8; ++c) acc[c] = fmaf(a0, w0[c], acc[c]);
#pragma unroll
      for (int c = 0; c < 8; ++c) acc[c] = fmaf(a1, w1[c], acc[c]);
#pragma unroll
      for (int c = 0; c < 8; ++c) acc[c] = fmaf(a2, w2[c], acc[c]);
#pragma unroll
      for (int c = 0; c < 8; ++c) acc[c] = fmaf(a3, w3[c], acc[c]);
    }
    __syncthreads();  // all GEMM reads done before next iteration's writes
#pragma unroll
    for (int c = 0; c < 8; ++c) {
      const double x = r64[c] - (double)acc[c];
      const double y = x + u[c];
      const double zn = fmin(fmax(y, 0.0), 1.0);
      u[c] = y - zn;
      z[c] = zn;
    }
  }

  // ---- epilogue: threshold, row count k, coeffs (x 1/128 folded), out = coeffs . V
  double xb[8];
  double cnt = 0.0;
#pragma unroll
  for (int c = 0; c < 8; ++c) {
    xb[c] = (z[c] > 0.5) ? 1.0 : 0.0;
    cnt += xb[c];
  }
  sCnt[w * 64 + lane] = (float)cnt;
  __syncthreads();
  double k = 0.0;
#pragma unroll
  for (int g = 0; g < 16; ++g) k += (double)sCnt[g * 64 + lane];
  const double rkS = (1.0 / 128.0) / (k + 1e-10);
#pragma unroll
  for (int c = 0; c < 8; ++c)
    sRT[(c0 + c) * 64 + lane] = (float)(xb[c] * rkS);
  __syncthreads();

  float oa[8];
#pragma unroll
  for (int c = 0; c < 8; ++c) oa[c] = 0.f;
  for (int m = 0; m < 128; m += 2) {
    const float a0 = sRT[(m + 0) * 64 + lane];
    const float a1 = sRT[(m + 1) * 64 + lane];
    const float* v0 = Vc + (m + 0) * 128;
    const float* v1 = Vc + (m + 1) * 128;
#pragma unroll
    for (int c = 0; c < 8; ++c) oa[c] = fmaf(a0, v0[c], oa[c]);
#pragma unroll
    for (int c = 0; c < 8; ++c) oa[c] = fmaf(a1, v1[c], oa[c]);
  }
#pragma unroll
  for (int q = 0; q < 2; ++q) {
    float4 o;
    o.x = oa[q * 4 + 0]; o.y = oa[q * 4 + 1];
    o.z = oa[q * 4 + 2]; o.w = oa[q * 4 + 3];
    *(float4*)(outb + lane * 128 + c0 + q * 4) = o;
  }
}

// ---------------------------------------------------------------------------
extern "C" void kernel_launch(void* const* d_in, const int* in_sizes, int n_in,
                              void* d_out, int out_size, void* d_ws, size_t ws_size,
                              hipStream_t stream) {
  const float* Q = (const float*)d_in[0];
  const float* V = (const float*)d_in[1];
  float* out = (float*)d_out;
  double* ws = (double*)d_ws;
  double* Mw = ws;                // 1 MiB (M; recycled as W32 after NS)
  double* Xa = ws + 131072;
  double* Xb = ws + 262144;
  double* Tw = ws + 393216;       // NS temp; recycled as VsT64. total 4 MiB

  mk_m64<<<128, 256, 0, stream>>>(V, Mw, Xa);
  double* pa = Xa;
  double* pb = Xb;
  for (int i = 0; i < 3; ++i) {  // Newton-Schulz f64: residual ||E||^(2^(k+1)) ~ 6e-20
    ns_gemm64<<<128, 256, 0, stream>>>(pa, Mw, Tw, pa, 0);  // T = X*M
    ns_gemm64<<<128, 256, 0, stream>>>(Tw, pa, pb, pa, 1);  // X' = 2X - T*X
    double* tmp = pa; pa = pb; pb = tmp;
  }
  float* W32 = (float*)Mw;
  double* VsT64 = Tw;
  prep_aux<<<64, 256, 0, stream>>>(pa, V, W32, VsT64);
  admm_corr<<<256, 1024, 0, stream>>>(Q, V, W32, VsT64, out);
}

// Round 5
// 451.506 us; speedup vs baseline: 2.1609x; 1.1066x over previous
//
#include <hip/hip_runtime.h>

#define NBATCH 8
#define NROWS 2048
#define MDIM 128
#define NITER 50
#define RSTR 132   // row stride (floats) for sR [row][j]; 132%32=4 -> 2-way alias = free

// ---------------------------------------------------------------------------
// mk_m64: M = I + 2*Vs*Vs^T (f64), X0 = 2I - M.
// grid 128 = 8b x 16 (32x32 tiles). Per-element fma chain identical to R2-R4.
// ---------------------------------------------------------------------------
__global__ __launch_bounds__(256) void mk_m64(const float* __restrict__ V,
                                              double* __restrict__ M,
                                              double* __restrict__ X0) {
  __shared__ double sA[32][130];
  __shared__ double sB[32][130];
  const int b = blockIdx.x >> 4, t = blockIdx.x & 15;
  const int i0 = (t >> 2) << 5, j0 = (t & 3) << 5;
  const float* Vb = V + b * MDIM * MDIM;
  const int tid = threadIdx.x;
  const double S = 1.0 / 128.0;
  for (int idx = tid; idx < 1024; idx += 256) {
    const int r = idx >> 5, c4 = (idx & 31) << 2;
    float4 v = *(const float4*)(Vb + (i0 + r) * MDIM + c4);
    sA[r][c4 + 0] = v.x * S; sA[r][c4 + 1] = v.y * S;
    sA[r][c4 + 2] = v.z * S; sA[r][c4 + 3] = v.w * S;
    float4 w = *(const float4*)(Vb + (j0 + r) * MDIM + c4);
    sB[r][c4 + 0] = w.x * S; sB[r][c4 + 1] = w.y * S;
    sB[r][c4 + 2] = w.z * S; sB[r][c4 + 3] = w.w * S;
  }
  __syncthreads();
  const int tx = tid & 15, ty = tid >> 4;
  double acc[2][2] = {};
  for (int k = 0; k < 128; ++k) {
    double a0 = sA[ty * 2 + 0][k], a1 = sA[ty * 2 + 1][k];
    double b0 = sB[tx * 2 + 0][k], b1 = sB[tx * 2 + 1][k];
    acc[0][0] = fma(a0, b0, acc[0][0]); acc[0][1] = fma(a0, b1, acc[0][1]);
    acc[1][0] = fma(a1, b0, acc[1][0]); acc[1][1] = fma(a1, b1, acc[1][1]);
  }
  double* Mb = M + b * 16384;
  double* Xb = X0 + b * 16384;
#pragma unroll
  for (int i = 0; i < 2; ++i)
#pragma unroll
    for (int j = 0; j < 2; ++j) {
      const int gi = i0 + ty * 2 + i, gj = j0 + tx * 2 + j;
      const double diag = (gi == gj) ? 1.0 : 0.0;
      const double mv = 2.0 * acc[i][j] + diag;
      Mb[gi * 128 + gj] = mv;
      Xb[gi * 128 + gj] = 2.0 * diag - mv;
    }
}

// ---------------------------------------------------------------------------
// ns_gemm64: C = A*B (B symmetric, read rows). mode1: C = 2*Xc - A*B.
// grid 128. Per-element fma chain identical to R2-R4.
// ---------------------------------------------------------------------------
__global__ __launch_bounds__(256) void ns_gemm64(const double* __restrict__ A,
                                                 const double* __restrict__ B,
                                                 double* __restrict__ C,
                                                 const double* __restrict__ Xc,
                                                 int mode) {
  __shared__ double sA[32][130];
  __shared__ double sB[32][130];
  const int b = blockIdx.x >> 4, t = blockIdx.x & 15;
  const int i0 = (t >> 2) << 5, j0 = (t & 3) << 5;
  const double* Ab = A + b * 16384;
  const double* Bb = B + b * 16384;
  const int tid = threadIdx.x;
  for (int idx = tid; idx < 2048; idx += 256) {
    const int r = idx >> 6, c2 = (idx & 63) << 1;
    *(double2*)&sA[r][c2] = *(const double2*)(Ab + (i0 + r) * 128 + c2);
    *(double2*)&sB[r][c2] = *(const double2*)(Bb + (j0 + r) * 128 + c2);
  }
  __syncthreads();
  const int tx = tid & 15, ty = tid >> 4;
  double acc[2][2] = {};
  for (int k = 0; k < 128; ++k) {
    double a0 = sA[ty * 2 + 0][k], a1 = sA[ty * 2 + 1][k];
    double b0 = sB[tx * 2 + 0][k], b1 = sB[tx * 2 + 1][k];
    acc[0][0] = fma(a0, b0, acc[0][0]); acc[0][1] = fma(a0, b1, acc[0][1]);
    acc[1][0] = fma(a1, b0, acc[1][0]); acc[1][1] = fma(a1, b1, acc[1][1]);
  }
  double* Cb = C + b * 16384;
  const double* Xcb = Xc + b * 16384;
#pragma unroll
  for (int i = 0; i < 2; ++i)
#pragma unroll
    for (int j = 0; j < 2; ++j) {
      const int gi = i0 + ty * 2 + i, gj = j0 + tx * 2 + j;
      double v = acc[i][j];
      if (mode != 0) v = 2.0 * Xcb[gi * 128 + gj] - v;
      Cb[gi * 128 + gj] = v;
    }
}

// ---------------------------------------------------------------------------
// prep_aux: W32 = fp32(I - Minv) ;  VsT64[d][m] = f64 V[m][d]/128
// ---------------------------------------------------------------------------
__global__ __launch_bounds__(256) void prep_aux(const double* __restrict__ Minv,
                                                const float* __restrict__ V,
                                                float* __restrict__ W32,
                                                double* __restrict__ VsT64) {
  const int b = blockIdx.x >> 3, ch = blockIdx.x & 7;
  const double* Mb = Minv + b * 16384;
  const float* Vb = V + b * 16384;
  float* Wb = W32 + b * 16384;
  double* Tb = VsT64 + b * 16384;
  const int base = ch * 2048;
  for (int k = threadIdx.x; k < 2048; k += 256) {
    const int idx = base + k;
    const int j = idx >> 7, c = idx & 127;
    const double diag = (j == c) ? 1.0 : 0.0;
    Wb[idx] = (float)(diag - Mb[idx]);
    Tb[idx] = (double)Vb[c * 128 + j] * (1.0 / 128.0);
  }
}

// ---------------------------------------------------------------------------
// admm_corr: persistent ADMM, f64 state + fp32 correction GEMM.
// grid 256; b = blockIdx&7 (XCD-aligned). 1024 threads = 16 waves (4/SIMD).
// lane = row; wave w -> cols c0 = 8w. rhs in LDS as [row][j] stride 132,
// read ds_read_b128 (4x fewer LDS ops than R4). W via wave-uniform s_loads.
// All per-element fma chains identical to R4 -> bit-identical trajectory.
// LDS: sR 33.8 KB + sCnt 4 KB.
// ---------------------------------------------------------------------------
__global__ __launch_bounds__(1024, 4) void admm_corr(const float* __restrict__ Q,
                                                     const float* __restrict__ V,
                                                     const float* __restrict__ W32,
                                                     const double* __restrict__ VsT64,
                                                     float* __restrict__ out) {
  __shared__ float sR[64 * RSTR];   // loop/epilogue: [row][j]; prologue: [d][row]
  __shared__ float sCnt[16 * 64];
  const int tid = threadIdx.x;
  const int b = blockIdx.x & 7;          // XCD id
  const int n0 = (blockIdx.x >> 3) << 6;
  const int lane = tid & 63;
  const int w = tid >> 6;                // 0..15
  const int c0 = w << 3;
  const int c0u = __builtin_amdgcn_readfirstlane(c0);
  const float* Qb = Q + ((size_t)(b * NROWS + n0)) * MDIM;
  const float* Wc = W32 + b * 16384 + c0u;
  const double* Vtc = VsT64 + b * 16384 + c0u;
  const float* Vc = V + b * 16384 + c0u;
  float* outb = out + ((size_t)(b * NROWS + n0)) * MDIM;

  // ---- stage Q^T (f32): sR[d*64 + r] = Q[n0+r][d]  (prologue layout)
  for (int idx = tid; idx < 2048; idx += 1024) {
    const int r = idx >> 5, d4 = (idx & 31) << 2;
    const float4 q = *(const float4*)(Qb + r * 128 + d4);
    sR[(d4 + 0) * 64 + r] = q.x;
    sR[(d4 + 1) * 64 + r] = q.y;
    sR[(d4 + 2) * 64 + r] = q.z;
    sR[(d4 + 3) * 64 + r] = q.w;
  }
  __syncthreads();

  // ---- P = -2 Q Vs^T + lam/m   (f64, same fma chain as R4 -> bit-identical)
  double p[8];
#pragma unroll
  for (int c = 0; c < 8; ++c) p[c] = 0.0;
  for (int d = 0; d < 128; ++d) {
    const double a = (double)sR[d * 64 + lane];
    const double* vt = Vtc + d * 128;
#pragma unroll
    for (int c = 0; c < 8; ++c) p[c] = fma(a, vt[c], p[c]);
  }
  const double LAM = 0.1 / 128.0;
#pragma unroll
  for (int c = 0; c < 8; ++c) p[c] = fma(-2.0, p[c], LAM);
  __syncthreads();  // prologue reads done; switch sR to [row][j] layout

  // ---- ADMM loop
  double z[8], u[8], r64[8];
#pragma unroll
  for (int c = 0; c < 8; ++c) { z[c] = 0.0; u[c] = 0.0; }

  for (int it = 0; it < NITER; ++it) {
    // write rhs row-major: sR[lane][c0..c0+7]
    {
      float4 w0, w1;
      double rv;
      rv = (z[0] - u[0]) - p[0]; r64[0] = rv; w0.x = (float)rv;
      rv = (z[1] - u[1]) - p[1]; r64[1] = rv; w0.y = (float)rv;
      rv = (z[2] - u[2]) - p[2]; r64[2] = rv; w0.z = (float)rv;
      rv = (z[3] - u[3]) - p[3]; r64[3] = rv; w0.w = (float)rv;
      rv = (z[4] - u[4]) - p[4]; r64[4] = rv; w1.x = (float)rv;
      rv = (z[5] - u[5]) - p[5]; r64[5] = rv; w1.y = (float)rv;
      rv = (z[6] - u[6]) - p[6]; r64[6] = rv; w1.z = (float)rv;
      rv = (z[7] - u[7]) - p[7]; r64[7] = rv; w1.w = (float)rv;
      *(float4*)&sR[lane * RSTR + c0 + 0] = w0;
      *(float4*)&sR[lane * RSTR + c0 + 4] = w1;
    }
    __syncthreads();
    float acc[8];
#pragma unroll
    for (int c = 0; c < 8; ++c) acc[c] = 0.f;
#pragma unroll 4
    for (int j4 = 0; j4 < 32; ++j4) {
      const float4 a4 = *(const float4*)&sR[lane * RSTR + (j4 << 2)];
      const float* w0 = Wc + ((j4 << 2) + 0) * 128;
      const float* w1 = Wc + ((j4 << 2) + 1) * 128;
      const float* w2 = Wc + ((j4 << 2) + 2) * 128;
      const float* w3 = Wc + ((j4 << 2) + 3) * 128;
#pragma unroll
      for (int c = 0; c < 8; ++c) acc[c] = fmaf(a4.x, w0[c], acc[c]);
#pragma unroll
      for (int c = 0; c < 8; ++c) acc[c] = fmaf(a4.y, w1[c], acc[c]);
#pragma unroll
      for (int c = 0; c < 8; ++c) acc[c] = fmaf(a4.z, w2[c], acc[c]);
#pragma unroll
      for (int c = 0; c < 8; ++c) acc[c] = fmaf(a4.w, w3[c], acc[c]);
    }
    __syncthreads();  // all GEMM reads done before next iteration's writes
#pragma unroll
    for (int c = 0; c < 8; ++c) {
      const double x = r64[c] - (double)acc[c];
      const double y = x + u[c];
      const double zn = fmin(fmax(y, 0.0), 1.0);
      u[c] = y - zn;
      z[c] = zn;
    }
  }

  // ---- epilogue: threshold, row count k, coeffs (x 1/128 folded), out = coeffs . V
  double xb[8];
  double cnt = 0.0;
#pragma unroll
  for (int c = 0; c < 8; ++c) {
    xb[c] = (z[c] > 0.5) ? 1.0 : 0.0;
    cnt += xb[c];
  }
  sCnt[w * 64 + lane] = (float)cnt;
  __syncthreads();
  double k = 0.0;
#pragma unroll
  for (int g = 0; g < 16; ++g) k += (double)sCnt[g * 64 + lane];
  const double rkS = (1.0 / 128.0) / (k + 1e-10);
  {
    float4 w0, w1;
    w0.x = (float)(xb[0] * rkS); w0.y = (float)(xb[1] * rkS);
    w0.z = (float)(xb[2] * rkS); w0.w = (float)(xb[3] * rkS);
    w1.x = (float)(xb[4] * rkS); w1.y = (float)(xb[5] * rkS);
    w1.z = (float)(xb[6] * rkS); w1.w = (float)(xb[7] * rkS);
    *(float4*)&sR[lane * RSTR + c0 + 0] = w0;
    *(float4*)&sR[lane * RSTR + c0 + 4] = w1;
  }
  __syncthreads();

  float oa[8];
#pragma unroll
  for (int c = 0; c < 8; ++c) oa[c] = 0.f;
#pragma unroll 4
  for (int m4 = 0; m4 < 32; ++m4) {
    const float4 a4 = *(const float4*)&sR[lane * RSTR + (m4 << 2)];
    const float* v0 = Vc + ((m4 << 2) + 0) * 128;
    const float* v1 = Vc + ((m4 << 2) + 1) * 128;
    const float* v2 = Vc + ((m4 << 2) + 2) * 128;
    const float* v3 = Vc + ((m4 << 2) + 3) * 128;
#pragma unroll
    for (int c = 0; c < 8; ++c) oa[c] = fmaf(a4.x, v0[c], oa[c]);
#pragma unroll
    for (int c = 0; c < 8; ++c) oa[c] = fmaf(a4.y, v1[c], oa[c]);
#pragma unroll
    for (int c = 0; c < 8; ++c) oa[c] = fmaf(a4.z, v2[c], oa[c]);
#pragma unroll
    for (int c = 0; c < 8; ++c) oa[c] = fmaf(a4.w, v3[c], oa[c]);
  }
#pragma unroll
  for (int q = 0; q < 2; ++q) {
    float4 o;
    o.x = oa[q * 4 + 0]; o.y = oa[q * 4 + 1];
    o.z = oa[q * 4 + 2]; o.w = oa[q * 4 + 3];
    *(float4*)(outb + lane * 128 + c0 + q * 4) = o;
  }
}

// ---------------------------------------------------------------------------
extern "C" void kernel_launch(void* const* d_in, const int* in_sizes, int n_in,
                              void* d_out, int out_size, void* d_ws, size_t ws_size,
                              hipStream_t stream) {
  const float* Q = (const float*)d_in[0];
  const float* V = (const float*)d_in[1];
  float* out = (float*)d_out;
  double* ws = (double*)d_ws;
  double* Mw = ws;                // 1 MiB (M; recycled as W32 after NS)
  double* Xa = ws + 131072;
  double* Xb = ws + 262144;
  double* Tw = ws + 393216;       // NS temp; recycled as VsT64. total 4 MiB

  mk_m64<<<128, 256, 0, stream>>>(V, Mw, Xa);
  double* pa = Xa;
  double* pb = Xb;
  for (int i = 0; i < 3; ++i) {  // Newton-Schulz f64: residual ||E||^(2^(k+1)) ~ 6e-20
    ns_gemm64<<<128, 256, 0, stream>>>(pa, Mw, Tw, pa, 0);  // T = X*M
    ns_gemm64<<<128, 256, 0, stream>>>(Tw, pa, pb, pa, 1);  // X' = 2X - T*X
    double* tmp = pa; pa = pb; pb = tmp;
  }
  float* W32 = (float*)Mw;
  double* VsT64 = Tw;
  prep_aux<<<64, 256, 0, stream>>>(pa, V, W32, VsT64);
  admm_corr<<<256, 1024, 0, stream>>>(Q, V, W32, VsT64, out);
}